// Round 11
// baseline (195.642 us; speedup 1.0000x reference)
//
#include <hip/hip_runtime.h>
#include <stdint.h>

typedef short v8s  __attribute__((ext_vector_type(8)));
typedef float v16f __attribute__((ext_vector_type(16)));

#define KS    7
#define KPTS  9
#define OCH   128
#define CCH   128
#define NB    32
#define HW    56
#define PAD   3

#define HBLK  2
#define ROWS  8             // HBLK + 6
#define WP    72
#define CCK   16            // c chunk per pass
#define NCC   8
#define HP    62
#define ROWB  (2*WP*8*2)        // [g2][w72][c8] bf16 = 2304 B per padded row
#define XS_B  (ROWS*ROWB)       // 18432 B = 18 KB-lines
#define SLOT_B 4096             // one tap's A image (4 lines)
#define AB_B  (4*SLOT_B)        // 16384 B ring
#define SMEM_B (XS_B + AB_B)    // 34816 B -> 4 blocks/CU

__device__ __forceinline__ unsigned short f2bf(float f) {
  unsigned int u = __builtin_bit_cast(unsigned int, f);
  u += 0x7fffu + ((u >> 16) & 1u);
  return (unsigned short)(u >> 16);
}

__device__ __forceinline__ void gl_lds16(const void* g, void* l) {
  __builtin_amdgcn_global_load_lds(
      (const __attribute__((address_space(1))) unsigned int*)g,
      (__attribute__((address_space(3))) unsigned int*)l, 16, 0, 0);
}

// Kernel construction: block = c (128), thread = o (128). Private 49-float row
// in LDS -> no atomics. kb = 32x32x16 A-fragment image, CCK=16:
// [cc8][tap49][mt4][lane64][8] bf16; lane l holds o = mt*32+(l&31),
// k_local = (l>>5)*8 + j (c = cc*16 + k_local). Conv A-read lane-linear 16B.
__global__ __launch_bounds__(128) void build_kern(
    const float* __restrict__ wgt, const float* __restrict__ P,
    unsigned short* __restrict__ kb) {
  __shared__ float sm[OCH*49];
  const int c = blockIdx.x, o = threadIdx.x;
  float* mine = &sm[o*49];
  #pragma unroll
  for (int j = 0; j < 49; ++j) mine[j] = 0.f;
  for (int k = 0; k < KPTS; ++k) {
    const float ph = fminf(fmaxf(P[c*KPTS + k], -3.f), 3.f) + 3.f;
    const float pw = fminf(fmaxf(P[CCH*KPTS + c*KPTS + k], -3.f), 3.f) + 3.f;
    const int ih = (int)floorf(ph), iw = (int)floorf(pw);
    const float rh = ph - (float)ih, rw = pw - (float)iw;
    const float wt = wgt[(o*CCH + c)*KPTS + k];
    mine[ih*KS + iw] += wt*(1.f-rh)*(1.f-rw);
    if (iw+1 < KS) mine[ih*KS + iw+1] += wt*(1.f-rh)*rw;
    if (ih+1 < KS) mine[(ih+1)*KS + iw] += wt*rh*(1.f-rw);
    if (ih+1 < KS && iw+1 < KS) mine[(ih+1)*KS + iw+1] += wt*rh*rw;
  }
  const int cc = c >> 4, cl = c & 15;
  const int g = cl >> 3, j = c & 7;
  const int mt = o >> 5, l5 = o & 31;
  // elem index: (((cc*49 + tap)*4 + mt)*64 + g*32 + l5)*8 + j
  const size_t base = (((size_t)cc*49*4 + mt)*64 + g*32 + l5)*8 + j;
  for (int tap = 0; tap < 49; ++tap)
    kb[base + (size_t)tap*2048] = f2bf(mine[tap]);
}

// x [n][c][h][w] f32 -> x_t [n][cc8][h'62][g2][w'72][c8] bf16 (pads zero).
// Conv B-frag reads are lane-linear 16B-stride at any kw -> conflict-free.
__global__ __launch_bounds__(256) void xpose(const float* __restrict__ x,
                                             unsigned short* __restrict__ xt) {
  __shared__ unsigned short lb[CCK][HW + 2];
  const int hp = blockIdx.x;
  const int cc = blockIdx.y;
  const int n  = blockIdx.z;
  const int t  = threadIdx.x;
  const int h  = hp - PAD;
  const bool valid = (unsigned)h < (unsigned)HW;
  if (valid) {
    const float* xb = x + ((size_t)(n*CCH + cc*CCK)*HW + h)*HW;
    #pragma unroll
    for (int k = 0; k < 4; ++k) {
      const int j = k*256 + t;               // 0..895
      if (j < CCK*HW) {
        const int c = j / HW, w = j % HW;
        lb[c][w] = f2bf(xb[(size_t)c*HW*HW + w]);
      }
    }
  }
  __syncthreads();
  unsigned short* orow = xt + (size_t)((n*NCC + cc)*HP + hp)*(2*WP*8);
  for (int q = t; q < 2*WP; q += 256) {      // q = g*72 + w'
    const int g = q / WP, wq = q % WP;
    v8s v = (v8s){0,0,0,0,0,0,0,0};
    const int w = wq - PAD;
    if (valid && (unsigned)w < (unsigned)HW) {
      #pragma unroll
      for (int jj = 0; jj < 8; ++jj) v[jj] = (short)lb[g*8 + jj][w];
    }
    *(v8s*)&orow[q*8] = v;
  }
}

// Read tap T's 4 A-frags from ring slot T&3 (lane-linear).
#define PF_A(T, FA)                                                           \
  {                                                                           \
    const unsigned short* ap = ab + (size_t)((T) & 3)*2048;                   \
    _Pragma("unroll")                                                         \
    for (int mt = 0; mt < 4; ++mt)                                            \
      FA[mt] = *(const v8s*)&ap[mt*512 + lane*8];                             \
  }

// Read tap T's 2 B-frags from xs (lane-linear 16B stride).
#define PF_B(T, FB)                                                           \
  {                                                                           \
    const int kh = (T)/7, kw = (T) - kh*7;                                    \
    const int r = wv + kh;                                                    \
    _Pragma("unroll")                                                         \
    for (int nt = 0; nt < 2; ++nt)                                            \
      FB[nt] = *(const v8s*)&xs[((size_t)(r*2 + g)*WP + nt*32 + kw + l5)*8];  \
  }

#define MFMA_T(FA, FB)                                                        \
  {                                                                           \
    __builtin_amdgcn_s_setprio(1);                                            \
    _Pragma("unroll")                                                         \
    for (int mt = 0; mt < 4; ++mt)                                            \
      _Pragma("unroll")                                                       \
      for (int nt = 0; nt < 2; ++nt)                                          \
        acc[mt][nt] = __builtin_amdgcn_mfma_f32_32x32x16_bf16(                \
            FA[mt], FB[nt], acc[mt][nt], 0, 0, 0);                            \
    __builtin_amdgcn_s_setprio(0);                                            \
  }

// Conv: grid 32 x 28 = 896 small blocks (128 thr = 2 waves), 34.8 KB LDS ->
// 4 blocks/CU co-resident: 4 INDEPENDENT barrier domains per CU drift over
// each other, overlapping one block's LDS-read phase with another's MFMA
// phase without compiler cooperation. Wave = one h-row, tile 128(o) x 64(w),
// K=16 per tap (CCK=16), 32x32x16 MFMA, all LDS reads lane-linear.
__global__ __launch_bounds__(128, 2) void dcls_conv(
    const unsigned short* __restrict__ xt, const unsigned short* __restrict__ kb,
    const float* __restrict__ bias, float* __restrict__ out)
{
  extern __shared__ char smem[];
  unsigned short* xs = (unsigned short*)smem;            // [r8][g2][72][8]
  unsigned short* ab = (unsigned short*)(smem + XS_B);   // ring of 4 x 4 KB

  const int n   = blockIdx.x;
  const int hb  = blockIdx.y;
  const int tid = threadIdx.x;
  const int lane = tid & 63;
  const int wv   = tid >> 6;        // 0..1 = h-row within block
  const int l5   = lane & 31;
  const int g    = lane >> 5;

  v16f acc[4][2];
  {
    v16f z;
    #pragma unroll
    for (int i = 0; i < 16; ++i) z[i] = 0.f;
    #pragma unroll
    for (int m = 0; m < 4; ++m)
      #pragma unroll
      for (int t = 0; t < 2; ++t)
        acc[m][t] = z;
  }

  v8s fa0[4], fa1[4], fb0[2], fb1[2];

  for (int cc = 0; cc < NCC; ++cc) {
    // ---- stage xs: 18 linear KB-lines (9 per wave) ----
    const char* src = (const char*)xt + (size_t)((n*NCC + cc)*HP + hb*HBLK)*ROWB;
    #pragma unroll
    for (int i = 0; i < 9; ++i)
      gl_lds16(src + (wv + i*2)*1024 + lane*16, (char*)xs + (wv + i*2)*1024);
    // ---- stage A(0), A(1): 4 lines each, 2 per wave ----
    const char* ks = (const char*)kb + (size_t)cc*49*SLOT_B;
    #pragma unroll
    for (int u = 0; u < 2; ++u)
      #pragma unroll
      for (int j = 0; j < 2; ++j)
        gl_lds16(ks + (size_t)u*SLOT_B + (wv*2 + j)*1024 + lane*16,
                 (char*)ab + (size_t)u*SLOT_B + (wv*2 + j)*1024);
    __syncthreads();

    PF_A(0, fa0)
    PF_B(0, fb0)

    #pragma unroll 1
    for (int p = 0; p < 24; ++p) {
      const int t0 = 2*p;
      // prefetch A(t0+2), A(t0+3) into slots freed at last barrier
      {
        const int tp = t0 + 2;
        #pragma unroll
        for (int j = 0; j < 2; ++j)
          gl_lds16(ks + (size_t)tp*SLOT_B + (wv*2 + j)*1024 + lane*16,
                   (char*)ab + (size_t)(tp & 3)*SLOT_B + (wv*2 + j)*1024);
        const int tq = t0 + 3;
        if (tq < 49) {
          #pragma unroll
          for (int j = 0; j < 2; ++j)
            gl_lds16(ks + (size_t)tq*SLOT_B + (wv*2 + j)*1024 + lane*16,
                     (char*)ab + (size_t)(tq & 3)*SLOT_B + (wv*2 + j)*1024);
        }
      }
      // frags(t0+1) under MFMA(t0)
      PF_A(t0 + 1, fa1)
      PF_B(t0 + 1, fb1)
      MFMA_T(fa0, fb0)
      // B(t0+2) pre-barrier (xs static) under MFMA(t0+1)
      PF_B(t0 + 2, fb0)
      MFMA_T(fa1, fb1)
      __syncthreads();          // drains prefetch DMA; slots recycle
      PF_A(t0 + 2, fa0)         // freshly-landed slot
    }
    MFMA_T(fa0, fb0)            // tap 48
    __syncthreads();            // protect xs/ring before next cc restage
  }

  // ---- epilogue: C/D 32x32: col(w)=lane&31, row(o)=(rr&3)+8*(rr>>2)+4*g ----
  const int h = hb*HBLK + wv;
  #pragma unroll
  for (int mt = 0; mt < 4; ++mt) {
    #pragma unroll
    for (int rr = 0; rr < 16; ++rr) {
      const int o = mt*32 + (rr & 3) + 8*(rr >> 2) + 4*g;
      const float bs = bias[o];
      out[((size_t)(n*OCH + o)*HW + h)*HW + l5] = acc[mt][0][rr] + bs;
      if (l5 < 24)
        out[((size_t)(n*OCH + o)*HW + h)*HW + 32 + l5] = acc[mt][1][rr] + bs;
    }
  }
}

extern "C" void kernel_launch(void* const* d_in, const int* in_sizes, int n_in,
                              void* d_out, int out_size, void* d_ws, size_t ws_size,
                              hipStream_t stream) {
  const float* x    = (const float*)d_in[0];
  const float* wgt  = (const float*)d_in[1];
  const float* P    = (const float*)d_in[2];
  const float* bias = (const float*)d_in[3];
  float* out = (float*)d_out;

  unsigned short* kb = (unsigned short*)d_ws;                       // 1.6 MB
  unsigned short* xt = (unsigned short*)((char*)d_ws + (2u<<20));   // 36.6 MB

  hipFuncSetAttribute((const void*)dcls_conv,
                      hipFuncAttributeMaxDynamicSharedMemorySize, SMEM_B);

  build_kern<<<CCH, OCH, 0, stream>>>(wgt, P, kb);
  xpose<<<dim3(HP, NCC, NB), 256, 0, stream>>>(x, xt);
  dcls_conv<<<dim3(NB, HW/HBLK), 128, SMEM_B, stream>>>(xt, kb, bias, out);
}

// Round 12
// 176.507 us; speedup vs baseline: 1.1084x; 1.1084x over previous
//
#include <hip/hip_runtime.h>
#include <stdint.h>

typedef short v8s  __attribute__((ext_vector_type(8)));
typedef float v16f __attribute__((ext_vector_type(16)));

#define KS    7
#define KPTS  9
#define OCH   128
#define CCH   128
#define NB    32
#define HW    56
#define PAD   3

#define HBLK  8
#define ROWS  14            // HBLK + 6
#define WP    72
#define CCK   32
#define NCC   4
#define HP    62
#define ROWB  (WP*CCK*2)        // 4608 B per padded x_t row
#define XS_B  (ROWS*ROWB)       // 64512 B = 63 KB-lines
#define AB_B  (8*8192)          // 65536 B: ring of 8 A-slots (8 KB each)
#define SMEM_B (XS_B + AB_B)    // 130048 B -> 1 block/CU

__device__ __forceinline__ unsigned short f2bf(float f) {
  unsigned int u = __builtin_bit_cast(unsigned int, f);
  u += 0x7fffu + ((u >> 16) & 1u);
  return (unsigned short)(u >> 16);
}

__device__ __forceinline__ void gl_lds16(const void* g, void* l) {
  __builtin_amdgcn_global_load_lds(
      (const __attribute__((address_space(1))) unsigned int*)g,
      (__attribute__((address_space(3))) unsigned int*)l, 16, 0, 0);
}

// Kernel construction: block = c (128), thread = o (128). Private 49-float row
// in LDS -> no atomics. kb = 32x32x16 A-fragment image (R9-validated):
// [cc][tap][f=kk*4+mt][lane64][8c]; lane l holds o=mt*32+(l&31),
// k(within cc) = kk*16 + (l>>5)*8 + j  -> conv A-read is lane-linear 16B.
__global__ __launch_bounds__(128) void build_kern(
    const float* __restrict__ wgt, const float* __restrict__ P,
    unsigned short* __restrict__ kb) {
  __shared__ float sm[OCH*49];
  const int c = blockIdx.x, o = threadIdx.x;
  float* mine = &sm[o*49];
  #pragma unroll
  for (int j = 0; j < 49; ++j) mine[j] = 0.f;
  for (int k = 0; k < KPTS; ++k) {
    const float ph = fminf(fmaxf(P[c*KPTS + k], -3.f), 3.f) + 3.f;
    const float pw = fminf(fmaxf(P[CCH*KPTS + c*KPTS + k], -3.f), 3.f) + 3.f;
    const int ih = (int)floorf(ph), iw = (int)floorf(pw);
    const float rh = ph - (float)ih, rw = pw - (float)iw;
    const float wt = wgt[(o*CCH + c)*KPTS + k];
    mine[ih*KS + iw] += wt*(1.f-rh)*(1.f-rw);
    if (iw+1 < KS) mine[ih*KS + iw+1] += wt*(1.f-rh)*rw;
    if (ih+1 < KS) mine[(ih+1)*KS + iw] += wt*rh*(1.f-rw);
    if (ih+1 < KS && iw+1 < KS) mine[(ih+1)*KS + iw+1] += wt*rh*rw;
  }
  const int cc = c >> 5, c32 = c & 31;
  const int kk = c32 >> 4, g = (c32 >> 3) & 1, j = c & 7;
  const int mt = o >> 5, l5 = o & 31;
  const size_t base = ((size_t)cc*49*8 + kk*4 + mt)*512 + (g*32 + l5)*8 + j;
  for (int tap = 0; tap < 49; ++tap)
    kb[base + (size_t)tap*4096] = f2bf(mine[tap]);
}

// x [n][c][h][w] f32 -> x_t [n][cc][h'][kk2][g2][w'72][c8] bf16 (pads zero).
// Conv B-frag reads are lane-linear 16B-stride at any kw -> conflict-free.
__global__ __launch_bounds__(256) void xpose(const float* __restrict__ x,
                                             unsigned short* __restrict__ xt) {
  __shared__ unsigned short lb[CCK][HW + 2];
  const int hp = blockIdx.x;
  const int cc = blockIdx.y;
  const int n  = blockIdx.z;
  const int t  = threadIdx.x;
  const int h  = hp - PAD;
  const bool valid = (unsigned)h < (unsigned)HW;
  if (valid) {
    const float* xb = x + ((size_t)(n*CCH + cc*CCK)*HW + h)*HW;
    #pragma unroll
    for (int k = 0; k < 7; ++k) {
      const int j = k*256 + t;
      const int c = j / HW, w = j % HW;
      lb[c][w] = f2bf(xb[(size_t)c*HW*HW + w]);
    }
  }
  __syncthreads();
  unsigned short* orow = xt + (size_t)((n*NCC + cc)*HP + hp)*(WP*4*8);
  for (int q = t; q < WP*4; q += 256) {   // q = (kk*2+g)*72 + w'
    const int kkg = q / WP, wq = q % WP;
    v8s v = (v8s){0,0,0,0,0,0,0,0};
    const int w = wq - PAD;
    if (valid && (unsigned)w < (unsigned)HW) {
      #pragma unroll
      for (int jj = 0; jj < 8; ++jj) v[jj] = (short)lb[kkg*8 + jj][w];
    }
    *(v8s*)&orow[q*8] = v;
  }
}

// m201-style tap phase: {12 lane-linear ds_reads -> SBAR -> s_barrier ->
// SBAR -> setprio(1) 16xMFMA setprio(0) -> SBAR -> s_barrier}. The release
// barrier lets waves issue tap T+1's reads while the matrix pipe drains.
#define TAP_PHASE(T, EXTRA)                                                   \
  {                                                                           \
    const int kh = (T)/7, kw = (T) - kh*7;                                    \
    const int r = wv + kh;                                                    \
    const unsigned short* ap = ab + (size_t)((T) & 7)*4096;                   \
    v8s a[8], b[4];                                                           \
    _Pragma("unroll")                                                         \
    for (int f = 0; f < 8; ++f)                                               \
      a[f] = *(const v8s*)&ap[f*512 + lane*8];                                \
    _Pragma("unroll")                                                         \
    for (int kk = 0; kk < 2; ++kk)                                            \
      _Pragma("unroll")                                                       \
      for (int nt = 0; nt < 2; ++nt)                                          \
        b[kk*2 + nt] = *(const v8s*)&xs[((size_t)((r*2 + kk)*2 + g)*WP +      \
                                         nt*32 + kw + l5)*8];                 \
    __builtin_amdgcn_sched_barrier(0);                                        \
    __builtin_amdgcn_s_barrier();       /* align: all waves issued reads */   \
    __builtin_amdgcn_sched_barrier(0);                                        \
    __builtin_amdgcn_s_setprio(1);                                            \
    _Pragma("unroll")                                                         \
    for (int kk = 0; kk < 2; ++kk)                                            \
      _Pragma("unroll")                                                       \
      for (int mt = 0; mt < 4; ++mt)                                          \
        _Pragma("unroll")                                                     \
        for (int nt = 0; nt < 2; ++nt)                                        \
          acc[mt][nt] = __builtin_amdgcn_mfma_f32_32x32x16_bf16(              \
              a[kk*4 + mt], b[kk*2 + nt], acc[mt][nt], 0, 0, 0);              \
    __builtin_amdgcn_s_setprio(0);                                            \
    __builtin_amdgcn_sched_barrier(0);                                        \
    EXTRA                                                                     \
    __builtin_amdgcn_s_barrier();       /* release: next reads vs drain */    \
    __builtin_amdgcn_sched_barrier(0);                                        \
  }

#define NOP_EXTRA
#define VM0_EXTRA asm volatile("s_waitcnt vmcnt(0)" ::: "memory");

// Conv: grid 32 x 7 = 224 (1 block/CU, uniform). 512 thr = 8 waves; wave =
// one h-row, tile M=128(o) x N=64(w), 32x32x16 MFMA, all LDS reads linear.
// Barrier-paired tap phases (m201 T3 shape) + 8-slot A-ring with counted
// prefetch: gl_lds issued at phase start, vmcnt(0) only at phase end (T4).
__global__ __launch_bounds__(512, 2) void dcls_conv(
    const unsigned short* __restrict__ xt, const unsigned short* __restrict__ kb,
    const float* __restrict__ bias, float* __restrict__ out)
{
  extern __shared__ char smem[];
  unsigned short* xs = (unsigned short*)smem;            // [r14][kk2][g2][72][8]
  unsigned short* ab = (unsigned short*)(smem + XS_B);   // ring of 8 frag-images

  const int n   = blockIdx.x;
  const int hb  = blockIdx.y;
  const int tid = threadIdx.x;
  const int lane = tid & 63;
  const int wv   = tid >> 6;        // 0..7 = h-row within block
  const int l5   = lane & 31;
  const int g    = lane >> 5;

  v16f acc[4][2];
  {
    v16f z;
    #pragma unroll
    for (int i = 0; i < 16; ++i) z[i] = 0.f;
    #pragma unroll
    for (int m = 0; m < 4; ++m)
      #pragma unroll
      for (int t = 0; t < 2; ++t)
        acc[m][t] = z;
  }

  for (int cc = 0; cc < NCC; ++cc) {
    // ---- stage xs: 63 linear KB-lines ----
    const char* src = (const char*)xt + (size_t)((n*NCC + cc)*HP + hb*HBLK)*ROWB;
    for (int i = wv; i < 63; i += 8)
      gl_lds16(src + i*1024 + lane*16, (char*)xs + i*1024);
    // ---- stage A slots 0..3 (taps 0..3), 1 line per wave per slot ----
    const char* ks = (const char*)kb + (size_t)cc*49*8192;
    #pragma unroll
    for (int u = 0; u < 4; ++u)
      gl_lds16(ks + (size_t)u*8192 + wv*1024 + lane*16,
               (char*)ab + (size_t)u*8192 + wv*1024 + lane*16);
    asm volatile("s_waitcnt vmcnt(0)" ::: "memory");
    __builtin_amdgcn_s_barrier();

    #pragma unroll 1
    for (int p = 0; p < 12; ++p) {
      const int tb = 4*p;
      // issue next phase's 4 A-tiles (other ring bank, drained last phase)
      #pragma unroll
      for (int j = 0; j < 4; ++j) {
        const int T = tb + 4 + j;
        if (T < 49)
          gl_lds16(ks + (size_t)T*8192 + wv*1024 + lane*16,
                   (char*)ab + (size_t)(T & 7)*8192 + wv*1024 + lane*16);
      }
      TAP_PHASE(tb,     NOP_EXTRA)
      TAP_PHASE(tb + 1, NOP_EXTRA)
      TAP_PHASE(tb + 2, NOP_EXTRA)
      TAP_PHASE(tb + 3, VM0_EXTRA)   // prefetches had a full phase in flight
    }
    TAP_PHASE(48, NOP_EXTRA)
  }

  // ---- epilogue: C/D 32x32: col(w)=lane&31, row(o)=(rr&3)+8*(rr>>2)+4*g ----
  const int h = hb*HBLK + wv;
  #pragma unroll
  for (int mt = 0; mt < 4; ++mt) {
    #pragma unroll
    for (int rr = 0; rr < 16; ++rr) {
      const int o = mt*32 + (rr & 3) + 8*(rr >> 2) + 4*g;
      const float bs = bias[o];
      out[((size_t)(n*OCH + o)*HW + h)*HW + l5] = acc[mt][0][rr] + bs;
      if (l5 < 24)
        out[((size_t)(n*OCH + o)*HW + h)*HW + 32 + l5] = acc[mt][1][rr] + bs;
    }
  }
}

extern "C" void kernel_launch(void* const* d_in, const int* in_sizes, int n_in,
                              void* d_out, int out_size, void* d_ws, size_t ws_size,
                              hipStream_t stream) {
  const float* x    = (const float*)d_in[0];
  const float* wgt  = (const float*)d_in[1];
  const float* P    = (const float*)d_in[2];
  const float* bias = (const float*)d_in[3];
  float* out = (float*)d_out;

  unsigned short* kb = (unsigned short*)d_ws;                       // 1.6 MB
  unsigned short* xt = (unsigned short*)((char*)d_ws + (2u<<20));   // 36.6 MB

  hipFuncSetAttribute((const void*)dcls_conv,
                      hipFuncAttributeMaxDynamicSharedMemorySize, SMEM_B);

  build_kern<<<CCH, OCH, 0, stream>>>(wgt, P, kb);
  xpose<<<dim3(HP, NCC, NB), 256, 0, stream>>>(x, xt);
  dcls_conv<<<dim3(NB, KS), 512, SMEM_B, stream>>>(xt, kb, bias, out);
}